// Round 1
// baseline (147.157 us; speedup 1.0000x reference)
//
#include <hip/hip_runtime.h>
#include <hip/hip_fp16.h>

// out[b,o] = sum_k x[b, conn[o,k]] * w[o,k]
// B=1024, In=8192, O=8192, K=32.
//
// Strategy: one block per 4-batch-row tile. Stage x[b0..b0+3][*] into LDS
// transposed as packed f16x4 (8 B per input column, 64 KiB total). Each
// gather index then needs ONE ds_read_b64 to serve 4 batch rows.
// Threads sweep outputs (lane-consecutive -> coalesced conn/w loads and
// out stores). fp32 weights + fp32 accumulation; only x is f16 in LDS.

constexpr int IN_F   = 8192;
constexpr int OUT_F  = 8192;
constexpr int KPER   = 32;
constexpr int BATCH  = 1024;
constexpr int ROWS   = 4;     // batch rows per block
constexpr int THREADS = 512;  // 8 waves

__global__ __launch_bounds__(THREADS, 2)
void psl_kernel(const float* __restrict__ x,
                const int*   __restrict__ conn,
                const float* __restrict__ w,
                float*       __restrict__ out) {
    __shared__ uint2 lds_x[IN_F];  // 64 KiB: [col] -> 4 batch rows as f16

    const int tid = threadIdx.x;
    const long b0 = (long)blockIdx.x * ROWS;

    const float* xr0 = x + (b0 + 0) * IN_F;
    const float* xr1 = x + (b0 + 1) * IN_F;
    const float* xr2 = x + (b0 + 2) * IN_F;
    const float* xr3 = x + (b0 + 3) * IN_F;

    // Stage: coalesced dword reads per row, pack 4 rows -> 8 B, one
    // ds_write_b64 per column (lane-stride 8 B: conflict-free).
    for (int c = tid; c < IN_F; c += THREADS) {
        __half2 h01 = __floats2half2_rn(xr0[c], xr1[c]);
        __half2 h23 = __floats2half2_rn(xr2[c], xr3[c]);
        uint2 pk;
        pk.x = *reinterpret_cast<unsigned*>(&h01);
        pk.y = *reinterpret_cast<unsigned*>(&h23);
        lds_x[c] = pk;
    }
    __syncthreads();

    float* or0 = out + (b0 + 0) * OUT_F;
    float* or1 = out + (b0 + 1) * OUT_F;
    float* or2 = out + (b0 + 2) * OUT_F;
    float* or3 = out + (b0 + 3) * OUT_F;

    for (int o = tid; o < OUT_F; o += THREADS) {
        const int4*   c4 = reinterpret_cast<const int4*>(conn + (size_t)o * KPER);
        const float4* w4 = reinterpret_cast<const float4*>(w + (size_t)o * KPER);

        float a0 = 0.f, a1 = 0.f, a2 = 0.f, a3 = 0.f;

#define GACC(IDX, WT)                                              \
        {                                                          \
            uint2 v = lds_x[(IDX)];                                \
            __half2 h01 = *reinterpret_cast<__half2*>(&v.x);       \
            __half2 h23 = *reinterpret_cast<__half2*>(&v.y);       \
            float2 f01 = __half22float2(h01);                      \
            float2 f23 = __half22float2(h23);                      \
            a0 = fmaf(f01.x, (WT), a0);                            \
            a1 = fmaf(f01.y, (WT), a1);                            \
            a2 = fmaf(f23.x, (WT), a2);                            \
            a3 = fmaf(f23.y, (WT), a3);                            \
        }

#pragma unroll
        for (int j = 0; j < KPER / 4; ++j) {
            const int4   ci = c4[j];
            const float4 wj = w4[j];
            GACC(ci.x, wj.x);
            GACC(ci.y, wj.y);
            GACC(ci.z, wj.z);
            GACC(ci.w, wj.w);
        }
#undef GACC

        or0[o] = a0;
        or1[o] = a1;
        or2[o] = a2;
        or3[o] = a3;
    }
}

extern "C" void kernel_launch(void* const* d_in, const int* in_sizes, int n_in,
                              void* d_out, int out_size, void* d_ws, size_t ws_size,
                              hipStream_t stream) {
    const float* x    = (const float*)d_in[0];
    const int*   conn = (const int*)d_in[1];
    const float* w    = (const float*)d_in[2];
    float*       out  = (float*)d_out;

    dim3 grid(BATCH / ROWS);  // 256 blocks, ~1 per CU
    psl_kernel<<<grid, THREADS, 0, stream>>>(x, conn, w, out);
}